// Round 1
// baseline (192.832 us; speedup 1.0000x reference)
//
#include <hip/hip_runtime.h>
#include <hip/hip_bf16.h>
#include <math.h>

#define BDIM 8192
#define DDIM 2048
#define CDIM 1000
#define NPAD 1024
#define BK   64

typedef __attribute__((ext_vector_type(8))) short short8;
typedef __attribute__((ext_vector_type(4))) float floatx4;

__device__ __forceinline__ unsigned short f2bf(float f) {
    union { float f; unsigned u; } a; a.f = f;
    unsigned u = a.u;
    // round-to-nearest-even fp32 -> bf16 (inputs are finite)
    u = (u + 0x7fff + ((u >> 16) & 1)) >> 16;
    return (unsigned short)u;
}

__device__ __forceinline__ void async_copy16(const void* gp, void* lp) {
    __builtin_amdgcn_global_load_lds(
        (const __attribute__((address_space(1))) void*)gp,
        (__attribute__((address_space(3))) void*)lp,
        16, 0, 0);
}

// ---- kernel 1: x fp32 -> bf16, 4 elems/thread, exact cover ----
__global__ __launch_bounds__(256) void cvt_x_kernel(
    const float4* __restrict__ x, ushort4* __restrict__ xb)
{
    int i = blockIdx.x * 256 + threadIdx.x;
    float4 v = x[i];
    ushort4 o;
    o.x = f2bf(v.x); o.y = f2bf(v.y); o.z = f2bf(v.z); o.w = f2bf(v.w);
    xb[i] = o;
}

// ---- kernel 2: W [2048,1000] fp32 -> Bt [1024,2048] bf16 (transposed, zero-padded) ----
__global__ __launch_bounds__(256) void cvt_w_kernel(
    const float* __restrict__ W, unsigned short* __restrict__ Bt)
{
    __shared__ float tile[32][33];
    int k0 = blockIdx.x * 32;   // k tile (64 tiles cover 2048)
    int n0 = blockIdx.y * 32;   // n tile (32 tiles cover 1024)
    int tx = threadIdx.x, ty = threadIdx.y;  // 32 x 8
    #pragma unroll
    for (int i = 0; i < 4; i++) {
        int k = k0 + ty + i * 8;
        int n = n0 + tx;
        tile[ty + i * 8][tx] = (n < CDIM) ? W[(size_t)k * CDIM + n] : 0.0f;
    }
    __syncthreads();
    #pragma unroll
    for (int i = 0; i < 4; i++) {
        int n = n0 + ty + i * 8;
        int k = k0 + tx;
        Bt[(size_t)n * DDIM + k] = f2bf(tile[tx][ty + i * 8]);
    }
}

// ---- kernel 3: bf16 GEMM (B^T layout), 128x128 tile, BK=64, 16x16x32 MFMA ----
// A  [8192,2048] bf16 row-major
// Bt [1024,2048] bf16 row-major (Bt[n][k] = W[k][n], rows 1000..1023 zero)
// C  [8192,1000] fp32 (ld = 1000), stores predicated col < 1000
__global__ __launch_bounds__(256, 2) void gemm_bt_kernel(
    const unsigned short* __restrict__ A,
    const unsigned short* __restrict__ Bt,
    float* __restrict__ C)
{
    __shared__ unsigned short As[128 * BK];
    __shared__ unsigned short Bs[128 * BK];

    const int t    = threadIdx.x;
    const int wave = t >> 6;
    const int lane = t & 63;
    const int wm   = wave & 1;          // 2x2 wave grid over 128x128
    const int wn   = wave >> 1;
    const int quad = lane >> 4;
    const int l16  = lane & 15;

    const int mBase = blockIdx.y * 128;
    const int nBase = blockIdx.x * 128;

    floatx4 acc[4][4] = {};

    // staging addresses: tile is 128 rows x 128 bytes; 256 threads x 16B = one
    // 32-row round; 4 rounds per tile. LDS dest = linear byteoff (wave-uniform
    // base + lane*16 as required by global_load_lds).
    const int byteoff = t * 16;         // 0..4095
    const int rowA    = byteoff >> 7;   // row within 32-row group
    const int colb    = byteoff & 127;
    const char* Ag = (const char*)A  + ((size_t)(mBase + rowA) * DDIM) * 2 + colb;
    const char* Bg = (const char*)Bt + ((size_t)(nBase + rowA) * DDIM) * 2 + colb;
    char* AsDst = (char*)As + byteoff;
    char* BsDst = (char*)Bs + byteoff;

    for (int kt = 0; kt < DDIM; kt += BK) {
        const char* a = Ag + kt * 2;
        const char* b = Bg + kt * 2;
        #pragma unroll
        for (int r = 0; r < 4; r++) {
            async_copy16(a + (size_t)r * 32 * DDIM * 2, AsDst + r * 4096);
            async_copy16(b + (size_t)r * 32 * DDIM * 2, BsDst + r * 4096);
        }
        __syncthreads();   // compiler emits vmcnt(0) drain before barrier

        #pragma unroll
        for (int ks = 0; ks < 2; ks++) {
            short8 af[4], bfr[4];
            #pragma unroll
            for (int mi = 0; mi < 4; mi++)
                af[mi] = *(const short8*)(As + (wm * 64 + mi * 16 + l16) * BK + ks * 32 + quad * 8);
            #pragma unroll
            for (int ni = 0; ni < 4; ni++)
                bfr[ni] = *(const short8*)(Bs + (wn * 64 + ni * 16 + l16) * BK + ks * 32 + quad * 8);
            #pragma unroll
            for (int mi = 0; mi < 4; mi++)
                #pragma unroll
                for (int ni = 0; ni < 4; ni++)
                    acc[mi][ni] = __builtin_amdgcn_mfma_f32_16x16x32_bf16(
                        af[mi], bfr[ni], acc[mi][ni], 0, 0, 0);
        }
        __syncthreads();
    }

    // epilogue: C/D layout col=lane&15, row=quad*4+reg (m89/m91-verified)
    #pragma unroll
    for (int mi = 0; mi < 4; mi++) {
        int row0 = mBase + wm * 64 + mi * 16 + quad * 4;
        #pragma unroll
        for (int ni = 0; ni < 4; ni++) {
            int col = nBase + wn * 64 + ni * 16 + l16;
            if (col < CDIM) {
                #pragma unroll
                for (int rg = 0; rg < 4; rg++)
                    C[(size_t)(row0 + rg) * CDIM + col] = acc[mi][ni][rg];
            }
        }
    }
}

// ---- kernel 4: per-row bias + LOO-logsumexp transform, in place on C ----
__global__ __launch_bounds__(256) void lse_kernel(
    float* __restrict__ C, const float* __restrict__ bias)
{
    const int row = blockIdx.x;
    const int t   = threadIdx.x;
    __shared__ float red[8];

    const bool valid = t < (CDIM / 4);   // 250 threads x 4 cols
    const int c0 = t * 4;

    float4 v = make_float4(-INFINITY, -INFINITY, -INFINITY, -INFINITY);
    if (valid) {
        v = *(const float4*)(C + (size_t)row * CDIM + c0);
        float4 bb = *(const float4*)(bias + c0);
        v.x += bb.x; v.y += bb.y; v.z += bb.z; v.w += bb.w;
    }

    // block max
    float m = fmaxf(fmaxf(v.x, v.y), fmaxf(v.z, v.w));
    #pragma unroll
    for (int off = 32; off > 0; off >>= 1)
        m = fmaxf(m, __shfl_down(m, off, 64));
    const int wave = t >> 6;
    if ((t & 63) == 0) red[wave] = m;
    __syncthreads();
    if (t == 0) red[4] = fmaxf(fmaxf(red[0], red[1]), fmaxf(red[2], red[3]));
    __syncthreads();
    const float M = red[4];

    // block sum of exp
    float4 e = make_float4(0.f, 0.f, 0.f, 0.f);
    float s = 0.f;
    if (valid) {
        e.x = expf(v.x - M); e.y = expf(v.y - M);
        e.z = expf(v.z - M); e.w = expf(v.w - M);
        s = e.x + e.y + e.z + e.w;
    }
    #pragma unroll
    for (int off = 32; off > 0; off >>= 1)
        s += __shfl_down(s, off, 64);
    if ((t & 63) == 0) red[wave] = s;
    __syncthreads();
    if (t == 0) red[4] = red[0] + red[1] + red[2] + red[3];
    __syncthreads();
    const float S   = red[4];
    const float lse = M + logf(S);
    const float invS = 1.0f / S;

    if (valid) {
        float4 o;
        o.x = (v.x - lse) - log1pf(-e.x * invS);
        o.y = (v.y - lse) - log1pf(-e.y * invS);
        o.z = (v.z - lse) - log1pf(-e.z * invS);
        o.w = (v.w - lse) - log1pf(-e.w * invS);
        *(float4*)(C + (size_t)row * CDIM + c0) = o;
    }
}

extern "C" void kernel_launch(void* const* d_in, const int* in_sizes, int n_in,
                              void* d_out, int out_size, void* d_ws, size_t ws_size,
                              hipStream_t stream) {
    const float* x = (const float*)d_in[0];   // [8192, 2048]
    const float* W = (const float*)d_in[1];   // [2048, 1000]
    const float* b = (const float*)d_in[2];   // [1000]
    float* out = (float*)d_out;               // [8192, 1000]

    unsigned short* xb = (unsigned short*)d_ws;                 // 8192*2048 bf16
    unsigned short* Bt = xb + (size_t)BDIM * DDIM;              // 1024*2048 bf16

    // 1) x -> bf16 (exact cover: 8192*2048/4 = 4,194,304 threads)
    cvt_x_kernel<<<16384, 256, 0, stream>>>((const float4*)x, (ushort4*)xb);

    // 2) W -> Bt (transpose + bf16 + zero-pad to 1024 rows)
    dim3 gw(DDIM / 32, NPAD / 32), bw(32, 8);
    cvt_w_kernel<<<gw, bw, 0, stream>>>(W, Bt);

    // 3) GEMM: grid x = N tiles (8), y = M tiles (64)
    dim3 gg(NPAD / 128, BDIM / 128);
    gemm_bt_kernel<<<gg, 256, 0, stream>>>(xb, Bt, out);

    // 4) per-row LOO-LSE transform (in place on d_out)
    lse_kernel<<<BDIM, 256, 0, stream>>>(out, b);
}

// Round 2
// 184.218 us; speedup vs baseline: 1.0468x; 1.0468x over previous
//
#include <hip/hip_runtime.h>
#include <hip/hip_bf16.h>
#include <math.h>

#define BDIM 8192
#define DDIM 2048
#define CDIM 1000
#define NPAD 1024
#define BK   64

// ws layout (bytes): xb bf16 [8192*2048] = 33554432 ; Bt bf16 [1024*2048] = 4194304 ;
// C1 fp32 partial [8192*1000] = 32768000 @ offset 37748736 ; total needed 70516736
#define WS_XB_BYTES   33554432ULL
#define WS_BT_BYTES    4194304ULL
#define WS_C1_OFFSET  37748736ULL
#define WS_NEED       70516736ULL

typedef __attribute__((ext_vector_type(8))) short short8;
typedef __attribute__((ext_vector_type(4))) float floatx4;

__device__ __forceinline__ unsigned short f2bf(float f) {
    union { float f; unsigned u; } a; a.f = f;
    unsigned u = a.u;
    u = (u + 0x7fff + ((u >> 16) & 1)) >> 16;   // RNE, finite inputs
    return (unsigned short)u;
}

__device__ __forceinline__ void async_copy16(const void* gp, void* lp) {
    __builtin_amdgcn_global_load_lds(
        (const __attribute__((address_space(1))) void*)gp,
        (__attribute__((address_space(3))) void*)lp,
        16, 0, 0);
}

// ---- kernel 1: fused x->bf16 (blocks 0..16383) and W->Bt transpose (blocks 16384..18431) ----
__global__ __launch_bounds__(256) void cvt_kernel(
    const float* __restrict__ x, unsigned short* __restrict__ xb,
    const float* __restrict__ W, unsigned short* __restrict__ Bt)
{
    const int blk = blockIdx.x;
    const int t   = threadIdx.x;
    if (blk < 16384) {
        int i = blk * 256 + t;
        float4 v = ((const float4*)x)[i];
        ushort4 o;
        o.x = f2bf(v.x); o.y = f2bf(v.y); o.z = f2bf(v.z); o.w = f2bf(v.w);
        ((ushort4*)xb)[i] = o;
    } else {
        __shared__ float tile[32][33];
        const int b2 = blk - 16384;          // 64 k-tiles x 32 n-tiles
        const int k0 = (b2 & 63) * 32;
        const int n0 = (b2 >> 6) * 32;
        const int tx = t & 31, ty = t >> 5;  // 32 x 8
        #pragma unroll
        for (int i = 0; i < 4; i++) {
            int k = k0 + ty + i * 8;
            int n = n0 + tx;
            tile[ty + i * 8][tx] = (n < CDIM) ? W[(size_t)k * CDIM + n] : 0.0f;
        }
        __syncthreads();
        #pragma unroll
        for (int i = 0; i < 4; i++) {
            int n = n0 + ty + i * 8;
            int k = k0 + tx;
            Bt[(size_t)n * DDIM + k] = f2bf(tile[tx][ty + i * 8]);
        }
    }
}

// ---- shared GEMM tile body: 128x128, BK=64, 16x16x32 bf16 MFMA ----
__device__ __forceinline__ void gemm_body(
    const unsigned short* __restrict__ A,
    const unsigned short* __restrict__ Bt,
    float* __restrict__ C,
    int mBase, int nBase, int kBase, int kIters,
    unsigned short* As, unsigned short* Bs)
{
    const int t    = threadIdx.x;
    const int wave = t >> 6;
    const int lane = t & 63;
    const int wm   = wave & 1;
    const int wn   = wave >> 1;
    const int quad = lane >> 4;
    const int l16  = lane & 15;

    floatx4 acc[4][4] = {};

    const int byteoff = t * 16;
    const int rowA    = byteoff >> 7;
    const int colb    = byteoff & 127;
    const char* Ag = (const char*)A  + ((size_t)(mBase + rowA) * DDIM + kBase) * 2 + colb;
    const char* Bg = (const char*)Bt + ((size_t)(nBase + rowA) * DDIM + kBase) * 2 + colb;
    char* AsDst = (char*)As + byteoff;
    char* BsDst = (char*)Bs + byteoff;

    for (int kt = 0; kt < kIters * BK; kt += BK) {
        const char* a = Ag + kt * 2;
        const char* b = Bg + kt * 2;
        #pragma unroll
        for (int r = 0; r < 4; r++) {
            async_copy16(a + (size_t)r * 32 * DDIM * 2, AsDst + r * 4096);
            async_copy16(b + (size_t)r * 32 * DDIM * 2, BsDst + r * 4096);
        }
        __syncthreads();

        #pragma unroll
        for (int ks = 0; ks < 2; ks++) {
            short8 af[4], bfr[4];
            #pragma unroll
            for (int mi = 0; mi < 4; mi++)
                af[mi] = *(const short8*)(As + (wm * 64 + mi * 16 + l16) * BK + ks * 32 + quad * 8);
            #pragma unroll
            for (int ni = 0; ni < 4; ni++)
                bfr[ni] = *(const short8*)(Bs + (wn * 64 + ni * 16 + l16) * BK + ks * 32 + quad * 8);
            #pragma unroll
            for (int mi = 0; mi < 4; mi++)
                #pragma unroll
                for (int ni = 0; ni < 4; ni++)
                    acc[mi][ni] = __builtin_amdgcn_mfma_f32_16x16x32_bf16(
                        af[mi], bfr[ni], acc[mi][ni], 0, 0, 0);
        }
        __syncthreads();
    }

    // C/D layout: col=lane&15, row=quad*4+reg
    #pragma unroll
    for (int mi = 0; mi < 4; mi++) {
        int row0 = mBase + wm * 64 + mi * 16 + quad * 4;
        #pragma unroll
        for (int ni = 0; ni < 4; ni++) {
            int col = nBase + wn * 64 + ni * 16 + l16;
            if (col < CDIM) {
                #pragma unroll
                for (int rg = 0; rg < 4; rg++)
                    C[(size_t)(row0 + rg) * CDIM + col] = acc[mi][ni][rg];
            }
        }
    }
}

// ---- split-K GEMM: grid 1024, XCD-swizzled; z=0 -> C0, z=1 -> C1 ----
__global__ __launch_bounds__(256, 4) void gemm_splitk_kernel(
    const unsigned short* __restrict__ A,
    const unsigned short* __restrict__ Bt,
    float* __restrict__ C0, float* __restrict__ C1)
{
    __shared__ unsigned short As[128 * BK];
    __shared__ unsigned short Bs[128 * BK];

    // swizzle: all 8 n-tiles of one (m,z) group land on one XCD, consecutively
    const int L   = blockIdx.x;        // 0..1023
    const int xcd = L & 7;
    const int s   = L >> 3;            // 0..127
    const int mz  = xcd * 16 + (s >> 3);  // 0..127
    const int n_t = s & 7;
    const int m_t = mz >> 1;           // 0..63
    const int z   = mz & 1;

    float* C = z ? C1 : C0;
    gemm_body(A, Bt, C, m_t * 128, n_t * 128, z * (DDIM / 2), (DDIM / 2) / BK, As, Bs);
}

// ---- single-K fallback: grid 512, XCD-swizzled ----
__global__ __launch_bounds__(256, 2) void gemm_single_kernel(
    const unsigned short* __restrict__ A,
    const unsigned short* __restrict__ Bt,
    float* __restrict__ C0)
{
    __shared__ unsigned short As[128 * BK];
    __shared__ unsigned short Bs[128 * BK];

    const int L   = blockIdx.x;        // 0..511
    const int xcd = L & 7;
    const int s   = L >> 3;            // 0..63
    const int m_t = xcd * 8 + (s >> 3);
    const int n_t = s & 7;

    gemm_body(A, Bt, C0, m_t * 128, n_t * 128, 0, DDIM / BK, As, Bs);
}

// ---- bias + LOO-logsumexp transform; optionally sums the split-K partial ----
__global__ __launch_bounds__(256) void lse_kernel(
    float* __restrict__ C, const float* C1,
    const float* __restrict__ bias, int split)
{
    const int row = blockIdx.x;
    const int t   = threadIdx.x;
    __shared__ float red[8];

    const bool valid = t < (CDIM / 4);   // 250 threads x 4 cols
    const int c0 = t * 4;

    float4 v = make_float4(-INFINITY, -INFINITY, -INFINITY, -INFINITY);
    if (valid) {
        v = *(const float4*)(C + (size_t)row * CDIM + c0);
        if (split) {
            float4 p = *(const float4*)(C1 + (size_t)row * CDIM + c0);
            v.x += p.x; v.y += p.y; v.z += p.z; v.w += p.w;
        }
        float4 bb = *(const float4*)(bias + c0);
        v.x += bb.x; v.y += bb.y; v.z += bb.z; v.w += bb.w;
    }

    float m = fmaxf(fmaxf(v.x, v.y), fmaxf(v.z, v.w));
    #pragma unroll
    for (int off = 32; off > 0; off >>= 1)
        m = fmaxf(m, __shfl_down(m, off, 64));
    const int wave = t >> 6;
    if ((t & 63) == 0) red[wave] = m;
    __syncthreads();
    if (t == 0) red[4] = fmaxf(fmaxf(red[0], red[1]), fmaxf(red[2], red[3]));
    __syncthreads();
    const float M = red[4];

    float4 e = make_float4(0.f, 0.f, 0.f, 0.f);
    float s = 0.f;
    if (valid) {
        e.x = expf(v.x - M); e.y = expf(v.y - M);
        e.z = expf(v.z - M); e.w = expf(v.w - M);
        s = e.x + e.y + e.z + e.w;
    }
    #pragma unroll
    for (int off = 32; off > 0; off >>= 1)
        s += __shfl_down(s, off, 64);
    if ((t & 63) == 0) red[wave] = s;
    __syncthreads();
    if (t == 0) red[4] = red[0] + red[1] + red[2] + red[3];
    __syncthreads();
    const float S    = red[4];
    const float lse  = M + logf(S);
    const float invS = 1.0f / S;

    if (valid) {
        float4 o;
        o.x = (v.x - lse) - log1pf(-e.x * invS);
        o.y = (v.y - lse) - log1pf(-e.y * invS);
        o.z = (v.z - lse) - log1pf(-e.z * invS);
        o.w = (v.w - lse) - log1pf(-e.w * invS);
        *(float4*)(C + (size_t)row * CDIM + c0) = o;
    }
}

extern "C" void kernel_launch(void* const* d_in, const int* in_sizes, int n_in,
                              void* d_out, int out_size, void* d_ws, size_t ws_size,
                              hipStream_t stream) {
    const float* x = (const float*)d_in[0];   // [8192, 2048]
    const float* W = (const float*)d_in[1];   // [2048, 1000]
    const float* b = (const float*)d_in[2];   // [1000]
    float* out = (float*)d_out;               // [8192, 1000]

    unsigned short* xb = (unsigned short*)d_ws;
    unsigned short* Bt = xb + (size_t)BDIM * DDIM;
    float* C1 = (float*)((char*)d_ws + WS_C1_OFFSET);
    const bool splitk = ws_size >= WS_NEED;   // constant across calls

    // 1) fused x->bf16 + W->Bt (16384 + 2048 blocks)
    cvt_kernel<<<18432, 256, 0, stream>>>(x, xb, W, Bt);

    // 2) GEMM
    if (splitk) {
        gemm_splitk_kernel<<<1024, 256, 0, stream>>>(xb, Bt, out, C1);
        lse_kernel<<<BDIM, 256, 0, stream>>>(out, C1, b, 1);
    } else {
        gemm_single_kernel<<<512, 256, 0, stream>>>(xb, Bt, out);
        lse_kernel<<<BDIM, 256, 0, stream>>>(out, nullptr, b, 0);
    }
}